// Round 9
// baseline (580.183 us; speedup 1.0000x reference)
//
#include <hip/hip_runtime.h>

#define B 2
#define T 2048
#define HID 1536
#define NH 12
#define DK 16
#define DV 128
#define BT (B * T)
#define EPS 1e-12f

typedef __attribute__((ext_vector_type(8))) short bf16x8;
typedef __attribute__((ext_vector_type(4))) float f32x4;

__device__ int g_taskctr;            // attn work-queue counter (init in phase 0)
__device__ unsigned g_bar_cnt = 0;   // grid barrier arrival count (self-resetting)
__device__ unsigned g_bar_gen = 0;   // grid barrier generation (monotonic across launches)

__device__ __forceinline__ unsigned short f2bf(float f) {
    unsigned int u = __float_as_uint(f);
    u += 0x7FFFu + ((u >> 16) & 1u);
    return (unsigned short)(u >> 16);
}

__device__ __forceinline__ unsigned int cvt_pk_bf16(float lo, float hi) {
    unsigned int r;
    asm("v_cvt_pk_bf16_f32 %0, %1, %2" : "=v"(r) : "v"(lo), "v"(hi));
    return r;
}

// ---------------------------------------------------------------------------
// Self-contained grid barrier (no cooperative runtime, graph-capture safe).
// Generation-based: gen cannot advance until all gridDim.x blocks increment
// cnt, so a pre-arrival gen snapshot is always the current generation (no
// ABA). cnt is reset before the release-store of gen+1, so next-barrier
// increments (ordered after the acquire-load of gen) land on 0.
// __threadfence() = agent-scope fence: release side drains vmcnt + writes
// back the XCD L2; acquire side invalidates — required because per-XCD L2s
// are not cross-coherent. Device-scope atomics proven working in R7's queue.
// ---------------------------------------------------------------------------
__device__ __forceinline__ void grid_barrier() {
    __syncthreads();
    if (threadIdx.x == 0) {
        __threadfence();   // release: make this block's stores visible device-wide
        unsigned gen = __hip_atomic_load(&g_bar_gen, __ATOMIC_RELAXED,
                                         __HIP_MEMORY_SCOPE_AGENT);
        unsigned n = __hip_atomic_fetch_add(&g_bar_cnt, 1u, __ATOMIC_ACQ_REL,
                                            __HIP_MEMORY_SCOPE_AGENT);
        if (n + 1u == gridDim.x) {
            __hip_atomic_store(&g_bar_cnt, 0u, __ATOMIC_RELAXED,
                               __HIP_MEMORY_SCOPE_AGENT);
            __hip_atomic_store(&g_bar_gen, gen + 1u, __ATOMIC_RELEASE,
                               __HIP_MEMORY_SCOPE_AGENT);
        } else {
            while (__hip_atomic_load(&g_bar_gen, __ATOMIC_ACQUIRE,
                                     __HIP_MEMORY_SCOPE_AGENT) == gen)
                __builtin_amdgcn_s_sleep(1);
        }
        __threadfence();   // acquire: invalidate stale cached lines before reading
    }
    __syncthreads();
}

// ---------------------------------------------------------------------------
// m97-style 128x128 bf16 GEMM tile body (BK=32, global_load_lds w=16,
// 16x16x32 MFMA, 4 waves x 4x4 frags). C bf16 row-major. [proven R0 body]
// ---------------------------------------------------------------------------
__device__ __forceinline__ void gemm_tile_bf16(const unsigned short* __restrict__ A,
                                               const unsigned short* __restrict__ Bm,
                                               unsigned short* __restrict__ C,
                                               int m0, int n0, int K, int ldc,
                                               unsigned short* As, unsigned short* Bs) {
    const int tid = threadIdx.x;
    const int wave = tid >> 6, lane = tid & 63;
    const int wm = (wave & 1) * 64, wn = (wave >> 1) * 64;
    const int fr = lane & 15;
    const int fk = (lane >> 4) * 8;

    f32x4 acc[4][4];
#pragma unroll
    for (int i = 0; i < 4; ++i)
#pragma unroll
        for (int j = 0; j < 4; ++j) acc[i][j] = (f32x4)0.f;

    const int c0 = tid, c1 = tid + 256;
    const int r0 = c0 >> 2, q0 = (c0 & 3) * 8;
    const int r1 = c1 >> 2, q1 = (c1 & 3) * 8;

    for (int k0 = 0; k0 < K; k0 += 32) {
        __builtin_amdgcn_global_load_lds(
            (const __attribute__((address_space(1))) void*)(A + (size_t)(m0 + r0) * K + k0 + q0),
            (__attribute__((address_space(3))) void*)(As + c0 * 8), 16, 0, 0);
        __builtin_amdgcn_global_load_lds(
            (const __attribute__((address_space(1))) void*)(A + (size_t)(m0 + r1) * K + k0 + q1),
            (__attribute__((address_space(3))) void*)(As + c1 * 8), 16, 0, 0);
        __builtin_amdgcn_global_load_lds(
            (const __attribute__((address_space(1))) void*)(Bm + (size_t)(n0 + r0) * K + k0 + q0),
            (__attribute__((address_space(3))) void*)(Bs + c0 * 8), 16, 0, 0);
        __builtin_amdgcn_global_load_lds(
            (const __attribute__((address_space(1))) void*)(Bm + (size_t)(n0 + r1) * K + k0 + q1),
            (__attribute__((address_space(3))) void*)(Bs + c1 * 8), 16, 0, 0);
        __syncthreads();

        bf16x8 af[4], bfr[4];
#pragma unroll
        for (int mb = 0; mb < 4; ++mb)
            af[mb] = *(const bf16x8*)(As + (wm + mb * 16 + fr) * 32 + fk);
#pragma unroll
        for (int nb = 0; nb < 4; ++nb)
            bfr[nb] = *(const bf16x8*)(Bs + (wn + nb * 16 + fr) * 32 + fk);
#pragma unroll
        for (int mb = 0; mb < 4; ++mb)
#pragma unroll
            for (int nb = 0; nb < 4; ++nb)
                acc[mb][nb] = __builtin_amdgcn_mfma_f32_16x16x32_bf16(
                    af[mb], bfr[nb], acc[mb][nb], 0, 0, 0);
        __syncthreads();
    }

    const int orow = (lane >> 4) * 4;
#pragma unroll
    for (int nb = 0; nb < 4; ++nb) {
        const int col = n0 + wn + nb * 16 + fr;
#pragma unroll
        for (int mb = 0; mb < 4; ++mb) {
            const int row = m0 + wm + mb * 16 + orow;
#pragma unroll
            for (int r = 0; r < 4; ++r)
                C[(size_t)(row + r) * ldc + col] = f2bf(acc[mb][nb][r]);
        }
    }
}

// Same body, fp32 C (for the final projection).
__device__ __forceinline__ void gemm_tile_f32(const unsigned short* __restrict__ A,
                                              const unsigned short* __restrict__ Bm,
                                              float* __restrict__ C,
                                              int m0, int n0, int K, int ldc,
                                              unsigned short* As, unsigned short* Bs) {
    const int tid = threadIdx.x;
    const int wave = tid >> 6, lane = tid & 63;
    const int wm = (wave & 1) * 64, wn = (wave >> 1) * 64;
    const int fr = lane & 15;
    const int fk = (lane >> 4) * 8;

    f32x4 acc[4][4];
#pragma unroll
    for (int i = 0; i < 4; ++i)
#pragma unroll
        for (int j = 0; j < 4; ++j) acc[i][j] = (f32x4)0.f;

    const int c0 = tid, c1 = tid + 256;
    const int r0 = c0 >> 2, q0 = (c0 & 3) * 8;
    const int r1 = c1 >> 2, q1 = (c1 & 3) * 8;

    for (int k0 = 0; k0 < K; k0 += 32) {
        __builtin_amdgcn_global_load_lds(
            (const __attribute__((address_space(1))) void*)(A + (size_t)(m0 + r0) * K + k0 + q0),
            (__attribute__((address_space(3))) void*)(As + c0 * 8), 16, 0, 0);
        __builtin_amdgcn_global_load_lds(
            (const __attribute__((address_space(1))) void*)(A + (size_t)(m0 + r1) * K + k0 + q1),
            (__attribute__((address_space(3))) void*)(As + c1 * 8), 16, 0, 0);
        __builtin_amdgcn_global_load_lds(
            (const __attribute__((address_space(1))) void*)(Bm + (size_t)(n0 + r0) * K + k0 + q0),
            (__attribute__((address_space(3))) void*)(Bs + c0 * 8), 16, 0, 0);
        __builtin_amdgcn_global_load_lds(
            (const __attribute__((address_space(1))) void*)(Bm + (size_t)(n0 + r1) * K + k0 + q1),
            (__attribute__((address_space(3))) void*)(Bs + c1 * 8), 16, 0, 0);
        __syncthreads();

        bf16x8 af[4], bfr[4];
#pragma unroll
        for (int mb = 0; mb < 4; ++mb)
            af[mb] = *(const bf16x8*)(As + (wm + mb * 16 + fr) * 32 + fk);
#pragma unroll
        for (int nb = 0; nb < 4; ++nb)
            bfr[nb] = *(const bf16x8*)(Bs + (wn + nb * 16 + fr) * 32 + fk);
#pragma unroll
        for (int mb = 0; mb < 4; ++mb)
#pragma unroll
            for (int nb = 0; nb < 4; ++nb)
                acc[mb][nb] = __builtin_amdgcn_mfma_f32_16x16x32_bf16(
                    af[mb], bfr[nb], acc[mb][nb], 0, 0, 0);
        __syncthreads();
    }

    const int orow = (lane >> 4) * 4;
#pragma unroll
    for (int nb = 0; nb < 4; ++nb) {
        const int col = n0 + wn + nb * 16 + fr;
#pragma unroll
        for (int mb = 0; mb < 4; ++mb) {
            const int row = m0 + wm + mb * 16 + orow;
#pragma unroll
            for (int r = 0; r < 4; ++r)
                C[(size_t)(row + r) * ldc + col] = acc[mb][nb][r];
        }
    }
}

// ---------------------------------------------------------------------------
// SINGLE NORMAL-LAUNCH KERNEL — all 4 phases, custom grid_barrier between.
// 512 blocks x 256 threads; __launch_bounds__(256,2) guarantees >=2 blocks/CU
// so all 512 are co-resident (required for the barrier).
// Phase 0: fp32->bf16 cvt (grid-stride) + queue-counter init.
// Phase 1: proj_qkv tiles (bid < 480)       [byte-identical R0 GEMM body]
// Phase 2: attn persistent queue            [byte-identical R7 body]
// Phase 3: proj_out tiles (bid < 384)
// ---------------------------------------------------------------------------
__global__ __launch_bounds__(256, 2) void fused_all(const float* __restrict__ hs,
                                                    const float* __restrict__ Wq,
                                                    const float* __restrict__ Wk,
                                                    const float* __restrict__ Wv,
                                                    const float* __restrict__ Wo,
                                                    unsigned short* __restrict__ hsb,
                                                    unsigned short* __restrict__ wqk,
                                                    unsigned short* __restrict__ wvb,
                                                    unsigned short* __restrict__ wob,
                                                    unsigned short* __restrict__ qkb,
                                                    unsigned short* __restrict__ vtg,
                                                    unsigned short* __restrict__ ybb,
                                                    float* __restrict__ out) {
    // 9348 shorts = 18,696 B. GEMM: As=[0,4096), Bs=[4096,8192).
    // attn: ss=[0,9216) ([2][64][72]), den=floats at 9216, task int at 9344.
    __shared__ __attribute__((aligned(16))) unsigned short smem[9348];
    const int bid = blockIdx.x;
    const int tid = threadIdx.x;

    // ---- phase 0: cvt (grid-stride) ----
    if (bid == 0 && tid == 0) g_taskctr = 512;
    for (int u = bid; u < 5664; u += 512) {
        int bx = u;
        const float* src;
        unsigned short* dst;
        if (bx < 3072)      { src = hs; dst = hsb; }
        else if (bx < 3216) { src = Wq; dst = wqk;          bx -= 3072; }
        else if (bx < 3360) { src = Wk; dst = wqk + 294912; bx -= 3216; }
        else if (bx < 4512) { src = Wv; dst = wvb;          bx -= 3360; }
        else                { src = Wo; dst = wob;          bx -= 4512; }
        const int i = (bx * 256 + tid) * 8;
        float4 a = *(const float4*)(src + i);
        float4 b = *(const float4*)(src + i + 4);
        *(ushort4*)(dst + i)     = make_ushort4(f2bf(a.x), f2bf(a.y), f2bf(a.z), f2bf(a.w));
        *(ushort4*)(dst + i + 4) = make_ushort4(f2bf(b.x), f2bf(b.y), f2bf(b.z), f2bf(b.w));
    }
    grid_barrier();

    // ---- phase 1: proj_qkv (480 tiles) ----
    {
        unsigned short* As = smem;
        unsigned short* Bs = smem + 4096;
        if (bid < 96) {
            gemm_tile_bf16(hsb, wqk, qkb, (bid / 3) * 128, (bid % 3) * 128, HID, 384, As, Bs);
        } else if (bid < 480) {
            const int vid = bid - 96;
            const int grp = vid / 48, sub = vid % 48;
            const int n_t = grp * 4 + (sub & 3), m_t = sub >> 2;
            gemm_tile_bf16(wvb, hsb, vtg, m_t * 128, n_t * 128, HID, BT, As, Bs);
        }
    }
    grid_barrier();

    // ---- phase 2: attn persistent queue (R7 body) ----
    {
        unsigned short (*ss)[64][72] = (unsigned short (*)[64][72])smem;
        float* den_lds = (float*)(smem + 9216);
        int* task_s = (int*)(smem + 9344);

        const int wave = tid >> 6, lane = tid & 63;
        const int fr = lane & 15, quad = lane >> 4;
        const int fk = quad * 8;
        const int fkk = (quad & 1) * 8;

        int c = bid;   // deterministic first claim (counter starts at 512)
        for (;;) {
            if (c >= 768) break;
            const int r = (c < 512) ? ((c & 1) ? 767 - (c >> 1) : (c >> 1)) : (c - 256);
            const int qt = 31 - r / 24;
            const int hb = r % 24;
            const int h  = hb >> 1;
            const int bi = hb & 1;

            if (tid < 64) den_lds[tid] = 0.f;

            const bf16x8 zf = {};
            bf16x8 qf[4];
#pragma unroll
            for (int nt = 0; nt < 4; ++nt) {
                qf[nt] = zf;
                if (quad < 2)
                    qf[nt] = *(const bf16x8*)&qkb[(size_t)(bi * T + qt * 64 + nt * 16 + fr) * 384
                                                  + h * DK + fk];
            }

            f32x4 oacc[2][4];
#pragma unroll
            for (int mt = 0; mt < 2; ++mt)
#pragma unroll
                for (int nt = 0; nt < 4; ++nt) oacc[mt][nt] = (f32x4)0.f;
            float denp[4] = {0.f, 0.f, 0.f, 0.f};

            const unsigned short* kbase = qkb + (size_t)(bi * T + wave * 16 + fr) * 384
                                          + 192 + h * DK + fkk;
            const unsigned short* vbase0 = vtg + (size_t)(h * DV + wave * 32 + fr) * BT
                                           + bi * T + fk;
            const unsigned short* vbase1 = vbase0 + (size_t)16 * BT;

            bf16x8 kf_n = *(const bf16x8*)kbase;
            bf16x8 vf_n[2][2];
            vf_n[0][0] = *(const bf16x8*)(vbase0);
            vf_n[0][1] = *(const bf16x8*)(vbase0 + 32);
            vf_n[1][0] = *(const bf16x8*)(vbase1);
            vf_n[1][1] = *(const bf16x8*)(vbase1 + 32);

            for (int kt = 0; kt <= qt; ++kt) {
                const int bsel = kt & 1;
                const bf16x8 kf = kf_n;
                bf16x8 vf[2][2];
                vf[0][0] = vf_n[0][0]; vf[0][1] = vf_n[0][1];
                vf[1][0] = vf_n[1][0]; vf[1][1] = vf_n[1][1];

                {
                    const int ktn = (kt < qt) ? kt + 1 : qt;
                    kf_n = *(const bf16x8*)(kbase + (size_t)ktn * 64 * 384);
                    const int off = ktn * 64;
                    vf_n[0][0] = *(const bf16x8*)(vbase0 + off);
                    vf_n[0][1] = *(const bf16x8*)(vbase0 + off + 32);
                    vf_n[1][0] = *(const bf16x8*)(vbase1 + off);
                    vf_n[1][1] = *(const bf16x8*)(vbase1 + off + 32);
                }

                f32x4 sa[4];
#pragma unroll
                for (int nt = 0; nt < 4; ++nt)
                    sa[nt] = __builtin_amdgcn_mfma_f32_16x16x32_bf16(kf, qf[nt], (f32x4)0.f,
                                                                     0, 0, 0);

#pragma unroll
                for (int nt = 0; nt < 4; ++nt) {
                    const int i = nt * 16 + fr;
                    float sv[4];
#pragma unroll
                    for (int rr = 0; rr < 4; ++rr) {
                        const float a = sa[nt][rr];
                        sv[rr] = fmaf(a, fmaf(a, 1.f / 32.f, 0.25f), 1.f);
                    }
                    if (kt == qt) {
#pragma unroll
                        for (int rr = 0; rr < 4; ++rr) {
                            const int j = wave * 16 + quad * 4 + rr;
                            if (j > i) sv[rr] = 0.f;
                        }
                    }
                    denp[nt] += (sv[0] + sv[1]) + (sv[2] + sv[3]);
                    uint2 pk;
                    pk.x = cvt_pk_bf16(sv[0], sv[1]);
                    pk.y = cvt_pk_bf16(sv[2], sv[3]);
                    *(uint2*)&ss[bsel][i][wave * 16 + quad * 4] = pk;
                }
                __syncthreads();

#pragma unroll
                for (int k2 = 0; k2 < 2; ++k2) {
                    bf16x8 sf[4];
#pragma unroll
                    for (int nt = 0; nt < 4; ++nt)
                        sf[nt] = *(const bf16x8*)&ss[bsel][nt * 16 + fr][k2 * 32 + fk];
#pragma unroll
                    for (int mt = 0; mt < 2; ++mt)
#pragma unroll
                        for (int nt = 0; nt < 4; ++nt)
                            oacc[mt][nt] = __builtin_amdgcn_mfma_f32_16x16x32_bf16(
                                vf[mt][k2], sf[nt], oacc[mt][nt], 0, 0, 0);
                }
            }

#pragma unroll
            for (int nt = 0; nt < 4; ++nt) {
                float v = denp[nt];
                v += __shfl_xor(v, 16);
                v += __shfl_xor(v, 32);
                if (quad == 0) atomicAdd(&den_lds[nt * 16 + fr], v);
            }
            __syncthreads();

#pragma unroll
            for (int nt = 0; nt < 4; ++nt) {
                const int i = nt * 16 + fr;
                const float rd = 1.f / (den_lds[i] + EPS);
                const size_t rowbase = (size_t)(bi * T + qt * 64 + i) * (NH * DV) + h * DV;
#pragma unroll
                for (int mt = 0; mt < 2; ++mt) {
                    const int cc = wave * 32 + mt * 16 + quad * 4;
                    const f32x4 o = oacc[mt][nt];
                    *(ushort4*)&ybb[rowbase + cc] = make_ushort4(f2bf(o[0] * rd), f2bf(o[1] * rd),
                                                                 f2bf(o[2] * rd), f2bf(o[3] * rd));
                }
            }

            __syncthreads();
            if (tid == 0) *task_s = atomicAdd(&g_taskctr, 1);
            __syncthreads();
            c = *task_s;
        }
    }
    grid_barrier();

    // ---- phase 3: proj_out (384 tiles) ----
    {
        unsigned short* As = smem;
        unsigned short* Bs = smem + 4096;
        if (bid < 384) {
            const int m_t = bid / 12, n_t = bid % 12;
            gemm_tile_f32(ybb, wob, out, m_t * 128, n_t * 128, HID, HID, As, Bs);
        }
    }
}

extern "C" void kernel_launch(void* const* d_in, const int* in_sizes, int n_in,
                              void* d_out, int out_size, void* d_ws, size_t ws_size,
                              hipStream_t stream) {
    (void)in_sizes; (void)n_in; (void)out_size; (void)ws_size;
    const float* hs = (const float*)d_in[0];
    const float* Wq = (const float*)d_in[1];
    const float* Wk = (const float*)d_in[2];
    const float* Wv = (const float*)d_in[3];
    const float* Wo = (const float*)d_in[4];
    float* out = (float*)d_out;

    // bf16 workspace (~51.5 MB)
    unsigned short* hsb = (unsigned short*)d_ws;        // [BT][HID]
    unsigned short* wqk = hsb + (size_t)BT * HID;       // [384][HID]  (Wq ; Wk)
    unsigned short* wvb = wqk + (size_t)384 * HID;      // [HID][HID]
    unsigned short* wob = wvb + (size_t)HID * HID;      // [HID][HID]
    unsigned short* qkb = wob + (size_t)HID * HID;      // [BT][384]
    unsigned short* vtg = qkb + (size_t)BT * 384;       // [HID][BT]  (V^T)
    unsigned short* ybb = vtg + (size_t)HID * BT;       // [BT][HID]

    fused_all<<<dim3(512), dim3(256), 0, stream>>>(hs, Wq, Wk, Wv, Wo,
                                                   hsb, wqk, wvb, wob,
                                                   qkb, vtg, ybb, out);
}

// Round 10
// 211.404 us; speedup vs baseline: 2.7444x; 2.7444x over previous
//
#include <hip/hip_runtime.h>

#define B 2
#define T 2048
#define HID 1536
#define NH 12
#define DK 16
#define DV 128
#define BT (B * T)
#define EPS 1e-12f

typedef __attribute__((ext_vector_type(8))) short bf16x8;
typedef __attribute__((ext_vector_type(4))) float f32x4;

__device__ int g_taskctr;   // attn work-queue counter (init to 512 by cvt_all)

__device__ __forceinline__ unsigned short f2bf(float f) {
    unsigned int u = __float_as_uint(f);
    u += 0x7FFFu + ((u >> 16) & 1u);
    return (unsigned short)(u >> 16);
}

__device__ __forceinline__ unsigned int cvt_pk_bf16(float lo, float hi) {
    unsigned int r;
    asm("v_cvt_pk_bf16_f32 %0, %1, %2" : "=v"(r) : "v"(lo), "v"(hi));
    return r;
}

// ---------------------------------------------------------------------------
// Fused fp32->bf16 for all 5 inputs. Segments in 2048-element blocks:
// hs 3072 | Wq 144 | Wk 144 | Wv 1152 | Wo 1152 = 5664 blocks.
// Wq+Wk land concatenated in wqk [384][1536]. Also resets the attn queue
// counter (stream-ordered before based_attn_mfma).
// ---------------------------------------------------------------------------
__global__ __launch_bounds__(256) void cvt_all(const float* __restrict__ hs,
                                               const float* __restrict__ Wq,
                                               const float* __restrict__ Wk,
                                               const float* __restrict__ Wv,
                                               const float* __restrict__ Wo,
                                               unsigned short* __restrict__ hsb,
                                               unsigned short* __restrict__ wqk,
                                               unsigned short* __restrict__ wvb,
                                               unsigned short* __restrict__ wob) {
    int bx = blockIdx.x;
    if (bx == 0 && threadIdx.x == 0) g_taskctr = 512;   // workers claim 0..511 statically
    const float* src;
    unsigned short* dst;
    if (bx < 3072)      { src = hs; dst = hsb; }
    else if (bx < 3216) { src = Wq; dst = wqk;          bx -= 3072; }
    else if (bx < 3360) { src = Wk; dst = wqk + 294912; bx -= 3216; }
    else if (bx < 4512) { src = Wv; dst = wvb;          bx -= 3360; }
    else                { src = Wo; dst = wob;          bx -= 4512; }
    const int i = (bx * 256 + threadIdx.x) * 8;
    float4 a = *(const float4*)(src + i);
    float4 b = *(const float4*)(src + i + 4);
    *(ushort4*)(dst + i)     = make_ushort4(f2bf(a.x), f2bf(a.y), f2bf(a.z), f2bf(a.w));
    *(ushort4*)(dst + i + 4) = make_ushort4(f2bf(b.x), f2bf(b.y), f2bf(b.z), f2bf(b.w));
}

// ---------------------------------------------------------------------------
// Generic m97-style 128x128 bf16 GEMM tile body (BK=32, global_load_lds w=16,
// 16x16x32 MFMA, 4 waves x 4x4 frags). C bf16 row-major, no store guards
// (M,N multiples of 128). [Round-0 version — proven local optimum.]
// ---------------------------------------------------------------------------
__device__ __forceinline__ void gemm_tile_bf16(const unsigned short* __restrict__ A,
                                               const unsigned short* __restrict__ Bm,
                                               unsigned short* __restrict__ C,
                                               int m0, int n0, int K, int ldc,
                                               unsigned short* As, unsigned short* Bs) {
    const int tid = threadIdx.x;
    const int wave = tid >> 6, lane = tid & 63;
    const int wm = (wave & 1) * 64, wn = (wave >> 1) * 64;
    const int fr = lane & 15;
    const int fk = (lane >> 4) * 8;

    f32x4 acc[4][4];
#pragma unroll
    for (int i = 0; i < 4; ++i)
#pragma unroll
        for (int j = 0; j < 4; ++j) acc[i][j] = (f32x4)0.f;

    const int c0 = tid, c1 = tid + 256;
    const int r0 = c0 >> 2, q0 = (c0 & 3) * 8;
    const int r1 = c1 >> 2, q1 = (c1 & 3) * 8;

    for (int k0 = 0; k0 < K; k0 += 32) {
        __builtin_amdgcn_global_load_lds(
            (const __attribute__((address_space(1))) void*)(A + (size_t)(m0 + r0) * K + k0 + q0),
            (__attribute__((address_space(3))) void*)(As + c0 * 8), 16, 0, 0);
        __builtin_amdgcn_global_load_lds(
            (const __attribute__((address_space(1))) void*)(A + (size_t)(m0 + r1) * K + k0 + q1),
            (__attribute__((address_space(3))) void*)(As + c1 * 8), 16, 0, 0);
        __builtin_amdgcn_global_load_lds(
            (const __attribute__((address_space(1))) void*)(Bm + (size_t)(n0 + r0) * K + k0 + q0),
            (__attribute__((address_space(3))) void*)(Bs + c0 * 8), 16, 0, 0);
        __builtin_amdgcn_global_load_lds(
            (const __attribute__((address_space(1))) void*)(Bm + (size_t)(n0 + r1) * K + k0 + q1),
            (__attribute__((address_space(3))) void*)(Bs + c1 * 8), 16, 0, 0);
        __syncthreads();

        bf16x8 af[4], bfr[4];
#pragma unroll
        for (int mb = 0; mb < 4; ++mb)
            af[mb] = *(const bf16x8*)(As + (wm + mb * 16 + fr) * 32 + fk);
#pragma unroll
        for (int nb = 0; nb < 4; ++nb)
            bfr[nb] = *(const bf16x8*)(Bs + (wn + nb * 16 + fr) * 32 + fk);
#pragma unroll
        for (int mb = 0; mb < 4; ++mb)
#pragma unroll
            for (int nb = 0; nb < 4; ++nb)
                acc[mb][nb] = __builtin_amdgcn_mfma_f32_16x16x32_bf16(
                    af[mb], bfr[nb], acc[mb][nb], 0, 0, 0);
        __syncthreads();
    }

    const int orow = (lane >> 4) * 4;
#pragma unroll
    for (int nb = 0; nb < 4; ++nb) {
        const int col = n0 + wn + nb * 16 + fr;
#pragma unroll
        for (int mb = 0; mb < 4; ++mb) {
            const int row = m0 + wm + mb * 16 + orow;
#pragma unroll
            for (int r = 0; r < 4; ++r)
                C[(size_t)(row + r) * ldc + col] = f2bf(acc[mb][nb][r]);
        }
    }
}

// ---------------------------------------------------------------------------
// Fused QK-proj + V^T-proj, one launch, 480 blocks (round-0 version):
//   bx <  96: qk[BT][384] = hsb @ wqk^T           (m-tile bx/3, n-tile bx%3)
//   bx >= 96: vt[HID][BT] = wvb @ hsb^T (V^T)      (4-wide n-supertile swizzle)
// ---------------------------------------------------------------------------
__global__ __launch_bounds__(256) void proj_qkv(const unsigned short* __restrict__ hsb,
                                                const unsigned short* __restrict__ wqk,
                                                const unsigned short* __restrict__ wvb,
                                                unsigned short* __restrict__ qkb,
                                                unsigned short* __restrict__ vtg) {
    __shared__ unsigned short As[128 * 32];
    __shared__ unsigned short Bs[128 * 32];
    const int bx = blockIdx.x;
    if (bx < 96) {
        gemm_tile_bf16(hsb, wqk, qkb, (bx / 3) * 128, (bx % 3) * 128, HID, 384, As, Bs);
    } else {
        const int vid = bx - 96;
        const int grp = vid / 48, sub = vid % 48;
        const int n_t = grp * 4 + (sub & 3), m_t = sub >> 2;
        gemm_tile_bf16(wvb, hsb, vtg, m_t * 128, n_t * 128, HID, BT, As, Bs);
    }
}

// ---------------------------------------------------------------------------
// Output projection: out[BT][HID] fp32 = ybb @ wob^T. (round-0 version)
// ---------------------------------------------------------------------------
__global__ __launch_bounds__(256) void proj_out(const unsigned short* __restrict__ A,
                                                const unsigned short* __restrict__ Bm,
                                                float* __restrict__ C) {
    __shared__ unsigned short As[128 * 32];
    __shared__ unsigned short Bs[128 * 32];
    const int tid = threadIdx.x;
    const int m0 = blockIdx.y * 128;
    const int n0 = blockIdx.x * 128;
    const int wave = tid >> 6, lane = tid & 63;
    const int wm = (wave & 1) * 64, wn = (wave >> 1) * 64;
    const int fr = lane & 15;
    const int fk = (lane >> 4) * 8;
    const int K = HID;

    f32x4 acc[4][4];
#pragma unroll
    for (int i = 0; i < 4; ++i)
#pragma unroll
        for (int j = 0; j < 4; ++j) acc[i][j] = (f32x4)0.f;

    const int c0 = tid, c1 = tid + 256;
    const int r0 = c0 >> 2, q0 = (c0 & 3) * 8;
    const int r1 = c1 >> 2, q1 = (c1 & 3) * 8;

    for (int k0 = 0; k0 < K; k0 += 32) {
        __builtin_amdgcn_global_load_lds(
            (const __attribute__((address_space(1))) void*)(A + (size_t)(m0 + r0) * K + k0 + q0),
            (__attribute__((address_space(3))) void*)(As + c0 * 8), 16, 0, 0);
        __builtin_amdgcn_global_load_lds(
            (const __attribute__((address_space(1))) void*)(A + (size_t)(m0 + r1) * K + k0 + q1),
            (__attribute__((address_space(3))) void*)(As + c1 * 8), 16, 0, 0);
        __builtin_amdgcn_global_load_lds(
            (const __attribute__((address_space(1))) void*)(Bm + (size_t)(n0 + r0) * K + k0 + q0),
            (__attribute__((address_space(3))) void*)(Bs + c0 * 8), 16, 0, 0);
        __builtin_amdgcn_global_load_lds(
            (const __attribute__((address_space(1))) void*)(Bm + (size_t)(n0 + r1) * K + k0 + q1),
            (__attribute__((address_space(3))) void*)(Bs + c1 * 8), 16, 0, 0);
        __syncthreads();

        bf16x8 af[4], bfr[4];
#pragma unroll
        for (int mb = 0; mb < 4; ++mb)
            af[mb] = *(const bf16x8*)(As + (wm + mb * 16 + fr) * 32 + fk);
#pragma unroll
        for (int nb = 0; nb < 4; ++nb)
            bfr[nb] = *(const bf16x8*)(Bs + (wn + nb * 16 + fr) * 32 + fk);
#pragma unroll
        for (int mb = 0; mb < 4; ++mb)
#pragma unroll
            for (int nb = 0; nb < 4; ++nb)
                acc[mb][nb] = __builtin_amdgcn_mfma_f32_16x16x32_bf16(
                    af[mb], bfr[nb], acc[mb][nb], 0, 0, 0);
        __syncthreads();
    }

    const int orow = (lane >> 4) * 4;
#pragma unroll
    for (int nb = 0; nb < 4; ++nb) {
        const int col = n0 + wn + nb * 16 + fr;
#pragma unroll
        for (int mb = 0; mb < 4; ++mb) {
            const int row = m0 + wm + mb * 16 + orow;
#pragma unroll
            for (int r = 0; r < 4; ++r)
                C[(size_t)(row + r) * HID + col] = acc[mb][nb][r];
        }
    }
}

// ---------------------------------------------------------------------------
// MFMA causal Taylor linear attention — persistent workers + queue (R7) with
// KVBLK=128: each iteration processes a PAIR of 64-key tiles (S for both ->
// one barrier -> O for both), halving barrier count and loop fixed cost per
// task at identical total work. ss keeps the proven [64][72] stride via 4
// buffers [sub][parity]. Mask generalized (kt>=qt; padded tile past qt masks
// to zero — R6-proven). Loads clamp to tile qt (in-bounds, masked anyway).
// __launch_bounds__(256,2) caps VGPR so 2 blocks/CU stay resident (LDS 37KB).
// ---------------------------------------------------------------------------
__global__ __launch_bounds__(256, 2) void based_attn_mfma(const unsigned short* __restrict__ qk,
                                                          const unsigned short* __restrict__ vt,
                                                          unsigned short* __restrict__ yb) {
    const int tid = threadIdx.x;
    const int wave = tid >> 6, lane = tid & 63;
    const int fr = lane & 15, quad = lane >> 4;
    const int fk = quad * 8;
    const int fkk = (quad & 1) * 8;   // clamped column for K A-frag (in-bounds)

    __shared__ __attribute__((aligned(16))) unsigned short ss[2][2][64][72];
    __shared__ float den_lds[64];
    __shared__ int task_s;

    int c = blockIdx.x;   // deterministic first claim (counter starts at 512)

    for (;;) {
        if (c >= 768) break;
        // claim -> rank: evens take heavy ranks ascending, odds take light
        // ranks from the bottom; dynamic pulls (c>=512) take mids descending.
        const int r = (c < 512) ? ((c & 1) ? 767 - (c >> 1) : (c >> 1)) : (c - 256);
        const int qt = 31 - r / 24;       // qt descending in rank
        const int hb = r % 24;
        const int h  = hb >> 1;
        const int bi = hb & 1;

        if (tid < 64) den_lds[tid] = 0.f;   // first kt-loop barrier makes visible

        const bf16x8 zf = {};
        // persistent Q B-frags: B[k][n] = Q[n=i][k], i = nt*16+fr; k>=16 zeroed
        bf16x8 qf[4];
#pragma unroll
        for (int nt = 0; nt < 4; ++nt) {
            qf[nt] = zf;
            if (quad < 2)
                qf[nt] = *(const bf16x8*)&qk[(size_t)(bi * T + qt * 64 + nt * 16 + fr) * 384
                                             + h * DK + fk];
        }

        f32x4 oacc[2][4];
#pragma unroll
        for (int mt = 0; mt < 2; ++mt)
#pragma unroll
            for (int nt = 0; nt < 4; ++nt) oacc[mt][nt] = (f32x4)0.f;
        float denp[4] = {0.f, 0.f, 0.f, 0.f};

        // base pointers (row 0 of this task's slice)
        const unsigned short* kbase = qk + (size_t)(bi * T + wave * 16 + fr) * 384
                                      + 192 + h * DK + fkk;
        const unsigned short* vbase0 = vt + (size_t)(h * DV + wave * 32 + fr) * BT + bi * T + fk;
        const unsigned short* vbase1 = vbase0 + (size_t)16 * BT;

        const int npair = (qt + 2) >> 1;   // ceil((qt+1)/2)

        // prologue: prefetch pair 0 (tiles 0 and min(1,qt))
        bf16x8 kf_n[2];
        bf16x8 vf_n[2][2][2];
        {
            const int t1 = (qt >= 1) ? 1 : 0;
            kf_n[0] = *(const bf16x8*)kbase;
            kf_n[1] = *(const bf16x8*)(kbase + (size_t)t1 * 64 * 384);
            const int o1 = t1 * 64;
            vf_n[0][0][0] = *(const bf16x8*)(vbase0);
            vf_n[0][0][1] = *(const bf16x8*)(vbase0 + 32);
            vf_n[0][1][0] = *(const bf16x8*)(vbase1);
            vf_n[0][1][1] = *(const bf16x8*)(vbase1 + 32);
            vf_n[1][0][0] = *(const bf16x8*)(vbase0 + o1);
            vf_n[1][0][1] = *(const bf16x8*)(vbase0 + o1 + 32);
            vf_n[1][1][0] = *(const bf16x8*)(vbase1 + o1);
            vf_n[1][1][1] = *(const bf16x8*)(vbase1 + o1 + 32);
        }

        for (int ip = 0; ip < npair; ++ip) {
            const int p = ip & 1;
            bf16x8 kf[2];
            bf16x8 vf[2][2][2];
            kf[0] = kf_n[0]; kf[1] = kf_n[1];
#pragma unroll
            for (int s = 0; s < 2; ++s)
#pragma unroll
                for (int mt = 0; mt < 2; ++mt)
#pragma unroll
                    for (int k2 = 0; k2 < 2; ++k2) vf[s][mt][k2] = vf_n[s][mt][k2];

            // prefetch pair ip+1 (clamped to qt; redundant on last iter)
            {
                int n0 = 2 * ip + 2; if (n0 > qt) n0 = qt;
                int n1 = 2 * ip + 3; if (n1 > qt) n1 = qt;
                kf_n[0] = *(const bf16x8*)(kbase + (size_t)n0 * 64 * 384);
                kf_n[1] = *(const bf16x8*)(kbase + (size_t)n1 * 64 * 384);
                const int o0 = n0 * 64, o1 = n1 * 64;
                vf_n[0][0][0] = *(const bf16x8*)(vbase0 + o0);
                vf_n[0][0][1] = *(const bf16x8*)(vbase0 + o0 + 32);
                vf_n[0][1][0] = *(const bf16x8*)(vbase1 + o0);
                vf_n[0][1][1] = *(const bf16x8*)(vbase1 + o0 + 32);
                vf_n[1][0][0] = *(const bf16x8*)(vbase0 + o1);
                vf_n[1][0][1] = *(const bf16x8*)(vbase0 + o1 + 32);
                vf_n[1][1][0] = *(const bf16x8*)(vbase1 + o1);
                vf_n[1][1][1] = *(const bf16x8*)(vbase1 + o1 + 32);
            }

            // S^T for both subtiles: wave owns j-strip [wave*16, wave*16+16)
#pragma unroll
            for (int s = 0; s < 2; ++s) {
                const int kt = 2 * ip + s;
                f32x4 sa[4];
#pragma unroll
                for (int nt = 0; nt < 4; ++nt)
                    sa[nt] = __builtin_amdgcn_mfma_f32_16x16x32_bf16(kf[s], qf[nt],
                                                                     (f32x4)0.f, 0, 0, 0);
#pragma unroll
                for (int nt = 0; nt < 4; ++nt) {
                    const int i = nt * 16 + fr;
                    float sv[4];
#pragma unroll
                    for (int rr = 0; rr < 4; ++rr) {
                        const float a = sa[nt][rr];
                        sv[rr] = fmaf(a, fmaf(a, 1.f / 32.f, 0.25f), 1.f);
                    }
                    if (kt >= qt) {   // diag-tile triangle, or all-zero padded tile
#pragma unroll
                        for (int rr = 0; rr < 4; ++rr) {
                            const int jg = kt * 64 + wave * 16 + quad * 4 + rr;
                            if (jg > qt * 64 + i) sv[rr] = 0.f;
                        }
                    }
                    denp[nt] += (sv[0] + sv[1]) + (sv[2] + sv[3]);
                    uint2 pk;
                    pk.x = cvt_pk_bf16(sv[0], sv[1]);
                    pk.y = cvt_pk_bf16(sv[2], sv[3]);
                    *(uint2*)&ss[s][p][i][wave * 16 + quad * 4] = pk;
                }
            }
            __syncthreads();

            // O^T += V^T S^T for both subtiles: wave owns c-chunk [wave*32,+32)
#pragma unroll
            for (int s = 0; s < 2; ++s) {
#pragma unroll
                for (int k2 = 0; k2 < 2; ++k2) {
                    bf16x8 sf[4];
#pragma unroll
                    for (int nt = 0; nt < 4; ++nt)
                        sf[nt] = *(const bf16x8*)&ss[s][p][nt * 16 + fr][k2 * 32 + fk];
#pragma unroll
                    for (int mt = 0; mt < 2; ++mt)
#pragma unroll
                        for (int nt = 0; nt < 4; ++nt)
                            oacc[mt][nt] = __builtin_amdgcn_mfma_f32_16x16x32_bf16(
                                vf[s][mt][k2], sf[nt], oacc[mt][nt], 0, 0, 0);
                }
            }
        }

        // den: quad-reduce (same fr), then cross-wave via LDS atomics
#pragma unroll
        for (int nt = 0; nt < 4; ++nt) {
            float v = denp[nt];
            v += __shfl_xor(v, 16);
            v += __shfl_xor(v, 32);
            if (quad == 0) atomicAdd(&den_lds[nt * 16 + fr], v);
        }
        __syncthreads();

        // y[i][c] = O^T[c][i] / den[i], bf16 row-major [BT][HID]
#pragma unroll
        for (int nt = 0; nt < 4; ++nt) {
            const int i = nt * 16 + fr;
            const float rd = 1.f / (den_lds[i] + EPS);
            const size_t rowbase = (size_t)(bi * T + qt * 64 + i) * (NH * DV) + h * DV;
#pragma unroll
            for (int mt = 0; mt < 2; ++mt) {
                const int cc = wave * 32 + mt * 16 + quad * 4;
                const f32x4 o = oacc[mt][nt];
                *(ushort4*)&yb[rowbase + cc] = make_ushort4(f2bf(o[0] * rd), f2bf(o[1] * rd),
                                                            f2bf(o[2] * rd), f2bf(o[3] * rd));
            }
        }

        // next task: barrier protects den_lds/task_s reuse against epilogue
        __syncthreads();
        if (tid == 0) task_s = atomicAdd(&g_taskctr, 1);
        __syncthreads();
        c = task_s;
    }
}

extern "C" void kernel_launch(void* const* d_in, const int* in_sizes, int n_in,
                              void* d_out, int out_size, void* d_ws, size_t ws_size,
                              hipStream_t stream) {
    (void)in_sizes; (void)n_in; (void)out_size; (void)ws_size;
    const float* hs = (const float*)d_in[0];
    const float* Wq = (const float*)d_in[1];
    const float* Wk = (const float*)d_in[2];
    const float* Wv = (const float*)d_in[3];
    const float* Wo = (const float*)d_in[4];
    float* out = (float*)d_out;

    // bf16 workspace (~51.5 MB)
    unsigned short* hsb = (unsigned short*)d_ws;        // [BT][HID]
    unsigned short* wqk = hsb + (size_t)BT * HID;       // [384][HID]  (Wq ; Wk)
    unsigned short* wvb = wqk + (size_t)384 * HID;      // [HID][HID]
    unsigned short* wob = wvb + (size_t)HID * HID;      // [HID][HID]
    unsigned short* qkb = wob + (size_t)HID * HID;      // [BT][384]
    unsigned short* vtg = qkb + (size_t)BT * 384;       // [HID][BT]  (V^T)
    unsigned short* ybb = vtg + (size_t)HID * BT;       // [BT][HID]

    dim3 blk(256);
    cvt_all<<<dim3(5664), blk, 0, stream>>>(hs, Wq, Wk, Wv, Wo, hsb, wqk, wvb, wob);

    // fused Q/K projection + V^T projection (128x128 tiles, 480 blocks)
    proj_qkv<<<dim3(480), blk, 0, stream>>>(hsb, wqk, wvb, qkb, vtg);

    // persistent-worker attention: 512 workers, 768 tasks via queue, KVBLK=128
    based_attn_mfma<<<dim3(512), blk, 0, stream>>>(qkb, vtg, ybb);

    // output projection (fp32 out, 128x128 tiles)
    proj_out<<<dim3(12, 32), blk, 0, stream>>>(ybb, wob, out);
}

// Round 11
// 208.865 us; speedup vs baseline: 2.7778x; 1.0122x over previous
//
#include <hip/hip_runtime.h>

#define B 2
#define T 2048
#define HID 1536
#define NH 12
#define DK 16
#define DV 128
#define BT (B * T)
#define EPS 1e-12f

typedef __attribute__((ext_vector_type(8))) short bf16x8;
typedef __attribute__((ext_vector_type(4))) float f32x4;

__device__ int g_taskctr;   // attn work-queue counter (init to 512 by cvt_all)

__device__ __forceinline__ unsigned short f2bf(float f) {
    unsigned int u = __float_as_uint(f);
    u += 0x7FFFu + ((u >> 16) & 1u);
    return (unsigned short)(u >> 16);
}

__device__ __forceinline__ unsigned int cvt_pk_bf16(float lo, float hi) {
    unsigned int r;
    asm("v_cvt_pk_bf16_f32 %0, %1, %2" : "=v"(r) : "v"(lo), "v"(hi));
    return r;
}

// ---------------------------------------------------------------------------
// Fused fp32->bf16 for all 5 inputs. Segments in 2048-element blocks:
// hs 3072 | Wq 144 | Wk 144 | Wv 1152 | Wo 1152 = 5664 blocks.
// Wq+Wk land concatenated in wqk [384][1536]. Also resets the attn queue
// counter (stream-ordered before based_attn_mfma).
// ---------------------------------------------------------------------------
__global__ __launch_bounds__(256) void cvt_all(const float* __restrict__ hs,
                                               const float* __restrict__ Wq,
                                               const float* __restrict__ Wk,
                                               const float* __restrict__ Wv,
                                               const float* __restrict__ Wo,
                                               unsigned short* __restrict__ hsb,
                                               unsigned short* __restrict__ wqk,
                                               unsigned short* __restrict__ wvb,
                                               unsigned short* __restrict__ wob) {
    int bx = blockIdx.x;
    if (bx == 0 && threadIdx.x == 0) g_taskctr = 512;   // workers claim 0..511 statically
    const float* src;
    unsigned short* dst;
    if (bx < 3072)      { src = hs; dst = hsb; }
    else if (bx < 3216) { src = Wq; dst = wqk;          bx -= 3072; }
    else if (bx < 3360) { src = Wk; dst = wqk + 294912; bx -= 3216; }
    else if (bx < 4512) { src = Wv; dst = wvb;          bx -= 3360; }
    else                { src = Wo; dst = wob;          bx -= 4512; }
    const int i = (bx * 256 + threadIdx.x) * 8;
    float4 a = *(const float4*)(src + i);
    float4 b = *(const float4*)(src + i + 4);
    *(ushort4*)(dst + i)     = make_ushort4(f2bf(a.x), f2bf(a.y), f2bf(a.z), f2bf(a.w));
    *(ushort4*)(dst + i + 4) = make_ushort4(f2bf(b.x), f2bf(b.y), f2bf(b.z), f2bf(b.w));
}

// ---------------------------------------------------------------------------
// Generic m97-style 128x128 bf16 GEMM tile body (BK=32, global_load_lds w=16,
// 16x16x32 MFMA, 4 waves x 4x4 frags). C bf16 row-major, no store guards
// (M,N multiples of 128). [Round-0 version — proven local optimum.]
// ---------------------------------------------------------------------------
__device__ __forceinline__ void gemm_tile_bf16(const unsigned short* __restrict__ A,
                                               const unsigned short* __restrict__ Bm,
                                               unsigned short* __restrict__ C,
                                               int m0, int n0, int K, int ldc,
                                               unsigned short* As, unsigned short* Bs) {
    const int tid = threadIdx.x;
    const int wave = tid >> 6, lane = tid & 63;
    const int wm = (wave & 1) * 64, wn = (wave >> 1) * 64;
    const int fr = lane & 15;
    const int fk = (lane >> 4) * 8;

    f32x4 acc[4][4];
#pragma unroll
    for (int i = 0; i < 4; ++i)
#pragma unroll
        for (int j = 0; j < 4; ++j) acc[i][j] = (f32x4)0.f;

    const int c0 = tid, c1 = tid + 256;
    const int r0 = c0 >> 2, q0 = (c0 & 3) * 8;
    const int r1 = c1 >> 2, q1 = (c1 & 3) * 8;

    for (int k0 = 0; k0 < K; k0 += 32) {
        __builtin_amdgcn_global_load_lds(
            (const __attribute__((address_space(1))) void*)(A + (size_t)(m0 + r0) * K + k0 + q0),
            (__attribute__((address_space(3))) void*)(As + c0 * 8), 16, 0, 0);
        __builtin_amdgcn_global_load_lds(
            (const __attribute__((address_space(1))) void*)(A + (size_t)(m0 + r1) * K + k0 + q1),
            (__attribute__((address_space(3))) void*)(As + c1 * 8), 16, 0, 0);
        __builtin_amdgcn_global_load_lds(
            (const __attribute__((address_space(1))) void*)(Bm + (size_t)(n0 + r0) * K + k0 + q0),
            (__attribute__((address_space(3))) void*)(Bs + c0 * 8), 16, 0, 0);
        __builtin_amdgcn_global_load_lds(
            (const __attribute__((address_space(1))) void*)(Bm + (size_t)(n0 + r1) * K + k0 + q1),
            (__attribute__((address_space(3))) void*)(Bs + c1 * 8), 16, 0, 0);
        __syncthreads();

        bf16x8 af[4], bfr[4];
#pragma unroll
        for (int mb = 0; mb < 4; ++mb)
            af[mb] = *(const bf16x8*)(As + (wm + mb * 16 + fr) * 32 + fk);
#pragma unroll
        for (int nb = 0; nb < 4; ++nb)
            bfr[nb] = *(const bf16x8*)(Bs + (wn + nb * 16 + fr) * 32 + fk);
#pragma unroll
        for (int mb = 0; mb < 4; ++mb)
#pragma unroll
            for (int nb = 0; nb < 4; ++nb)
                acc[mb][nb] = __builtin_amdgcn_mfma_f32_16x16x32_bf16(
                    af[mb], bfr[nb], acc[mb][nb], 0, 0, 0);
        __syncthreads();
    }

    const int orow = (lane >> 4) * 4;
#pragma unroll
    for (int nb = 0; nb < 4; ++nb) {
        const int col = n0 + wn + nb * 16 + fr;
#pragma unroll
        for (int mb = 0; mb < 4; ++mb) {
            const int row = m0 + wm + mb * 16 + orow;
#pragma unroll
            for (int r = 0; r < 4; ++r)
                C[(size_t)(row + r) * ldc + col] = f2bf(acc[mb][nb][r]);
        }
    }
}

// ---------------------------------------------------------------------------
// Fused QK-proj + V^T-proj, one launch, 480 blocks (round-0 version):
//   bx <  96: qk[BT][384] = hsb @ wqk^T           (m-tile bx/3, n-tile bx%3)
//   bx >= 96: vt[HID][BT] = wvb @ hsb^T (V^T)      (4-wide n-supertile swizzle)
// ---------------------------------------------------------------------------
__global__ __launch_bounds__(256) void proj_qkv(const unsigned short* __restrict__ hsb,
                                                const unsigned short* __restrict__ wqk,
                                                const unsigned short* __restrict__ wvb,
                                                unsigned short* __restrict__ qkb,
                                                unsigned short* __restrict__ vtg) {
    __shared__ unsigned short As[128 * 32];
    __shared__ unsigned short Bs[128 * 32];
    const int bx = blockIdx.x;
    if (bx < 96) {
        gemm_tile_bf16(hsb, wqk, qkb, (bx / 3) * 128, (bx % 3) * 128, HID, 384, As, Bs);
    } else {
        const int vid = bx - 96;
        const int grp = vid / 48, sub = vid % 48;
        const int n_t = grp * 4 + (sub & 3), m_t = sub >> 2;
        gemm_tile_bf16(wvb, hsb, vtg, m_t * 128, n_t * 128, HID, BT, As, Bs);
    }
}

// ---------------------------------------------------------------------------
// Output projection: out[BT][HID] fp32 = ybb @ wob^T.
// 128x96 tiles -> grid 16x32 = 512 blocks = EXACTLY 2/CU (kills the 33% tail
// waste of the 384-block 128x128 version: 384 = 256 + 128 meant round 2 ran
// at half occupancy). 4 waves x 4x3 frags (per-wave 64x48); B-tile 96x32
// staged with 1.5 chunks/thread (waves 0-1 issue the second chunk).
// ---------------------------------------------------------------------------
__global__ __launch_bounds__(256) void proj_out(const unsigned short* __restrict__ A,
                                                const unsigned short* __restrict__ Bm,
                                                float* __restrict__ C) {
    __shared__ unsigned short As[128 * 32];
    __shared__ unsigned short Bs[96 * 32];
    const int tid = threadIdx.x;
    const int m0 = blockIdx.y * 128;
    const int n0 = blockIdx.x * 96;
    const int wave = tid >> 6, lane = tid & 63;
    const int wm = (wave & 1) * 64, wn = (wave >> 1) * 48;
    const int fr = lane & 15;
    const int fk = (lane >> 4) * 8;
    const int K = HID;

    f32x4 acc[4][3];
#pragma unroll
    for (int i = 0; i < 4; ++i)
#pragma unroll
        for (int j = 0; j < 3; ++j) acc[i][j] = (f32x4)0.f;

    const int c0 = tid, c1 = tid + 256;
    const int r0 = c0 >> 2, q0 = (c0 & 3) * 8;   // A rows 0..63 / B rows 0..63
    const int r1 = c1 >> 2, q1 = (c1 & 3) * 8;   // A rows 64..127 / B rows 64..95

    for (int k0 = 0; k0 < K; k0 += 32) {
        // A tile: 128x32 = 512 chunks, 2/thread
        __builtin_amdgcn_global_load_lds(
            (const __attribute__((address_space(1))) void*)(A + (size_t)(m0 + r0) * K + k0 + q0),
            (__attribute__((address_space(3))) void*)(As + c0 * 8), 16, 0, 0);
        __builtin_amdgcn_global_load_lds(
            (const __attribute__((address_space(1))) void*)(A + (size_t)(m0 + r1) * K + k0 + q1),
            (__attribute__((address_space(3))) void*)(As + c1 * 8), 16, 0, 0);
        // B tile: 96x32 = 384 chunks: chunk tid for all, chunk tid+256 for
        // waves 0-1 only (wave-uniform predicate; full waves stay active).
        __builtin_amdgcn_global_load_lds(
            (const __attribute__((address_space(1))) void*)(Bm + (size_t)(n0 + r0) * K + k0 + q0),
            (__attribute__((address_space(3))) void*)(Bs + c0 * 8), 16, 0, 0);
        if (wave < 2)
            __builtin_amdgcn_global_load_lds(
                (const __attribute__((address_space(1))) void*)(Bm + (size_t)(n0 + r1) * K + k0 + q1),
                (__attribute__((address_space(3))) void*)(Bs + c1 * 8), 16, 0, 0);
        __syncthreads();

        bf16x8 af[4], bfr[3];
#pragma unroll
        for (int mb = 0; mb < 4; ++mb)
            af[mb] = *(const bf16x8*)(As + (wm + mb * 16 + fr) * 32 + fk);
#pragma unroll
        for (int nb = 0; nb < 3; ++nb)
            bfr[nb] = *(const bf16x8*)(Bs + (wn + nb * 16 + fr) * 32 + fk);
#pragma unroll
        for (int mb = 0; mb < 4; ++mb)
#pragma unroll
            for (int nb = 0; nb < 3; ++nb)
                acc[mb][nb] = __builtin_amdgcn_mfma_f32_16x16x32_bf16(
                    af[mb], bfr[nb], acc[mb][nb], 0, 0, 0);
        __syncthreads();
    }

    const int orow = (lane >> 4) * 4;
#pragma unroll
    for (int nb = 0; nb < 3; ++nb) {
        const int col = n0 + wn + nb * 16 + fr;
#pragma unroll
        for (int mb = 0; mb < 4; ++mb) {
            const int row = m0 + wm + mb * 16 + orow;
#pragma unroll
            for (int r = 0; r < 4; ++r)
                C[(size_t)(row + r) * HID + col] = acc[mb][nb][r];
        }
    }
}

// ---------------------------------------------------------------------------
// MFMA causal Taylor linear attention — PERSISTENT WORKERS + TASK QUEUE.
// [Round-7 version verbatim — best measured: 46.2us. R10's KVBLK=128 variant
// regressed (prefetch state too deep for 2 blocks/CU); reverted.]
//   512 4-wave workers (2/CU steady). Task = (qt,h,bi), 768 total, work
//   = qt+1 key-tile iterations. Static first claim c = blockIdx:
//     c even -> heavy rank c/2 (qt descending), c odd -> light rank 767-c/2
//   so every even/odd pair totals exactly 33 iterations. Remaining 256 mid
//   tasks pulled LPT via device-global atomic counter.
// ---------------------------------------------------------------------------
__global__ __launch_bounds__(256) void based_attn_mfma(const unsigned short* __restrict__ qk,
                                                       const unsigned short* __restrict__ vt,
                                                       unsigned short* __restrict__ yb) {
    const int tid = threadIdx.x;
    const int wave = tid >> 6, lane = tid & 63;
    const int fr = lane & 15, quad = lane >> 4;
    const int fk = quad * 8;
    const int fkk = (quad & 1) * 8;   // clamped column for K A-frag (in-bounds)

    __shared__ __attribute__((aligned(16))) unsigned short ss[2][64][72];
    __shared__ float den_lds[64];
    __shared__ int task_s;

    int c = blockIdx.x;   // deterministic first claim (counter starts at 512)

    for (;;) {
        if (c >= 768) break;
        // claim -> rank: evens take heavy ranks ascending, odds take light
        // ranks from the bottom; dynamic pulls (c>=512) take mids descending.
        const int r = (c < 512) ? ((c & 1) ? 767 - (c >> 1) : (c >> 1)) : (c - 256);
        const int qt = 31 - r / 24;       // qt descending in rank
        const int hb = r % 24;
        const int h  = hb >> 1;
        const int bi = hb & 1;

        if (tid < 64) den_lds[tid] = 0.f;   // first kt-loop barrier makes visible

        const bf16x8 zf = {};
        // persistent Q B-frags: B[k][n] = Q[n=i][k], i = nt*16+fr; k>=16 zeroed
        bf16x8 qf[4];
#pragma unroll
        for (int nt = 0; nt < 4; ++nt) {
            qf[nt] = zf;
            if (quad < 2)
                qf[nt] = *(const bf16x8*)&qk[(size_t)(bi * T + qt * 64 + nt * 16 + fr) * 384
                                             + h * DK + fk];
        }

        f32x4 oacc[2][4];
#pragma unroll
        for (int mt = 0; mt < 2; ++mt)
#pragma unroll
            for (int nt = 0; nt < 4; ++nt) oacc[mt][nt] = (f32x4)0.f;
        float denp[4] = {0.f, 0.f, 0.f, 0.f};

        // base pointers (row 0 of this task's slice)
        const unsigned short* kbase = qk + (size_t)(bi * T + wave * 16 + fr) * 384
                                      + 192 + h * DK + fkk;
        const unsigned short* vbase0 = vt + (size_t)(h * DV + wave * 32 + fr) * BT + bi * T + fk;
        const unsigned short* vbase1 = vbase0 + (size_t)16 * BT;

        // prologue: prefetch kt=0
        bf16x8 kf_n = *(const bf16x8*)kbase;
        bf16x8 vf_n[2][2];
        vf_n[0][0] = *(const bf16x8*)(vbase0);
        vf_n[0][1] = *(const bf16x8*)(vbase0 + 32);
        vf_n[1][0] = *(const bf16x8*)(vbase1);
        vf_n[1][1] = *(const bf16x8*)(vbase1 + 32);

        for (int kt = 0; kt <= qt; ++kt) {
            const int bsel = kt & 1;
            const bf16x8 kf = kf_n;
            bf16x8 vf[2][2];
            vf[0][0] = vf_n[0][0]; vf[0][1] = vf_n[0][1];
            vf[1][0] = vf_n[1][0]; vf[1][1] = vf_n[1][1];

            // prefetch kt+1 (clamped on last iteration; redundant but in-bounds)
            {
                const int ktn = (kt < qt) ? kt + 1 : qt;
                kf_n = *(const bf16x8*)(kbase + (size_t)ktn * 64 * 384);
                const int off = ktn * 64;
                vf_n[0][0] = *(const bf16x8*)(vbase0 + off);
                vf_n[0][1] = *(const bf16x8*)(vbase0 + off + 32);
                vf_n[1][0] = *(const bf16x8*)(vbase1 + off);
                vf_n[1][1] = *(const bf16x8*)(vbase1 + off + 32);
            }

            // S^T: wave owns j-strip [wave*16, wave*16+16)
            f32x4 sa[4];
#pragma unroll
            for (int nt = 0; nt < 4; ++nt)
                sa[nt] = __builtin_amdgcn_mfma_f32_16x16x32_bf16(kf, qf[nt], (f32x4)0.f, 0, 0, 0);

#pragma unroll
            for (int nt = 0; nt < 4; ++nt) {
                const int i = nt * 16 + fr;
                float sv[4];
#pragma unroll
                for (int rr = 0; rr < 4; ++rr) {
                    const float a = sa[nt][rr];
                    sv[rr] = fmaf(a, fmaf(a, 1.f / 32.f, 0.25f), 1.f);
                }
                if (kt == qt) {   // wave-uniform: causal mask only on diag tile
#pragma unroll
                    for (int rr = 0; rr < 4; ++rr) {
                        const int j = wave * 16 + quad * 4 + rr;
                        if (j > i) sv[rr] = 0.f;
                    }
                }
                denp[nt] += (sv[0] + sv[1]) + (sv[2] + sv[3]);
                uint2 pk;
                pk.x = cvt_pk_bf16(sv[0], sv[1]);
                pk.y = cvt_pk_bf16(sv[2], sv[3]);
                *(uint2*)&ss[bsel][i][wave * 16 + quad * 4] = pk;
            }
            __syncthreads();

            // O^T += V^T S^T : wave owns c-chunk [wave*32, wave*32+32)
#pragma unroll
            for (int k2 = 0; k2 < 2; ++k2) {
                bf16x8 sf[4];
#pragma unroll
                for (int nt = 0; nt < 4; ++nt)
                    sf[nt] = *(const bf16x8*)&ss[bsel][nt * 16 + fr][k2 * 32 + fk];
#pragma unroll
                for (int mt = 0; mt < 2; ++mt)
#pragma unroll
                    for (int nt = 0; nt < 4; ++nt)
                        oacc[mt][nt] = __builtin_amdgcn_mfma_f32_16x16x32_bf16(
                            vf[mt][k2], sf[nt], oacc[mt][nt], 0, 0, 0);
            }
        }

        // den: quad-reduce (same fr), then cross-wave via LDS atomics
#pragma unroll
        for (int nt = 0; nt < 4; ++nt) {
            float v = denp[nt];
            v += __shfl_xor(v, 16);
            v += __shfl_xor(v, 32);
            if (quad == 0) atomicAdd(&den_lds[nt * 16 + fr], v);
        }
        __syncthreads();

        // y[i][c] = O^T[c][i] / den[i], bf16 row-major [BT][HID]
#pragma unroll
        for (int nt = 0; nt < 4; ++nt) {
            const int i = nt * 16 + fr;
            const float rd = 1.f / (den_lds[i] + EPS);
            const size_t rowbase = (size_t)(bi * T + qt * 64 + i) * (NH * DV) + h * DV;
#pragma unroll
            for (int mt = 0; mt < 2; ++mt) {
                const int cc = wave * 32 + mt * 16 + quad * 4;
                const f32x4 o = oacc[mt][nt];
                *(ushort4*)&yb[rowbase + cc] = make_ushort4(f2bf(o[0] * rd), f2bf(o[1] * rd),
                                                            f2bf(o[2] * rd), f2bf(o[3] * rd));
            }
        }

        // next task: barrier protects den_lds/task_s reuse against epilogue
        __syncthreads();
        if (tid == 0) task_s = atomicAdd(&g_taskctr, 1);
        __syncthreads();
        c = task_s;
    }
}

extern "C" void kernel_launch(void* const* d_in, const int* in_sizes, int n_in,
                              void* d_out, int out_size, void* d_ws, size_t ws_size,
                              hipStream_t stream) {
    (void)in_sizes; (void)n_in; (void)out_size; (void)ws_size;
    const float* hs = (const float*)d_in[0];
    const float* Wq = (const float*)d_in[1];
    const float* Wk = (const float*)d_in[2];
    const float* Wv = (const float*)d_in[3];
    const float* Wo = (const float*)d_in[4];
    float* out = (float*)d_out;

    // bf16 workspace (~51.5 MB)
    unsigned short* hsb = (unsigned short*)d_ws;        // [BT][HID]
    unsigned short* wqk = hsb + (size_t)BT * HID;       // [384][HID]  (Wq ; Wk)
    unsigned short* wvb = wqk + (size_t)384 * HID;      // [HID][HID]
    unsigned short* wob = wvb + (size_t)HID * HID;      // [HID][HID]
    unsigned short* qkb = wob + (size_t)HID * HID;      // [BT][384]
    unsigned short* vtg = qkb + (size_t)BT * 384;       // [HID][BT]  (V^T)
    unsigned short* ybb = vtg + (size_t)HID * BT;       // [BT][HID]

    dim3 blk(256);
    cvt_all<<<dim3(5664), blk, 0, stream>>>(hs, Wq, Wk, Wv, Wo, hsb, wqk, wvb, wob);

    // fused Q/K projection + V^T projection (128x128 tiles, 480 blocks)
    proj_qkv<<<dim3(480), blk, 0, stream>>>(hsb, wqk, wvb, qkb, vtg);

    // persistent-worker attention: 512 workers, 768 tasks via queue (R7 exact)
    based_attn_mfma<<<dim3(512), blk, 0, stream>>>(qkb, vtg, ybb);

    // output projection (fp32 out, 128x96 tiles, 512 blocks = 2/CU exact)
    proj_out<<<dim3(16, 32), blk, 0, stream>>>(ybb, wob, out);
}